// Round 4
// baseline (489.521 us; speedup 1.0000x reference)
//
#include <hip/hip_runtime.h>
#include <math.h>

// ---------------- constants ----------------
#define NN 512
#define CSD 384
#define CZD 128
#define HD 8
#define CD 128
#define EPSV 1e-8f
#define INFV 100000.0f

// ---------------- ws float offsets ----------------
#define OFF_QN    ((size_t)0)
#define OFF_TR    ((size_t)2048)
#define OFF_QSQ   ((size_t)3584)
#define OFF_KSQ   ((size_t)7680)
#define OFF_ROWT  ((size_t)11776)
#define OFF_COLT  ((size_t)15872)
#define OFF_SB    ((size_t)19968)
#define OFF_QBUF  ((size_t)52736)
#define OFF_KV    ((size_t)577024)
#define OFF_QPTS  ((size_t)1625600)
#define OFF_KPTS  ((size_t)1723904)
#define OFF_VGG   ((size_t)1822208)
#define OFF_ZB    ((size_t)2346496)   // zb 2,097,152 fl; dead after k_scorefill -> reused as Vp
#define OFF_A     ((size_t)4443648)
#define OFF_X     ((size_t)6540800)
// union region (lifetimes disjoint, stream-ordered):
#define OFF_QPR   (OFF_X)                    // dead after k_geom
#define OFF_KPR   (OFF_X + 98304)            // dead after k_geom
#define OFF_VGR   (OFF_X + 196608)           // dead after k_geom
#define OFF_U     (OFF_X)                    // written k_uv, dead after scorefill
#define OFF_V     (OFF_X + 655360)           // row-major Vr, dead after scorefill
#define OFF_AZ    (OFF_X)                    // 524288 fl, zeroed post-scorefill
#define OFF_O     (OFF_X + 524288)
#define OFF_OG    (OFF_X + 1048576)
#define OFF_FEATS (OFF_X + 1572864)
#define OFF_VP    (OFF_ZB)

__device__ __forceinline__ void qrot(const float q[4], const float* v, float* out) {
    float qw = q[0], qx = q[1], qy = q[2], qz = q[3];
    float ux = qy*v[2] - qz*v[1];
    float uy = qz*v[0] - qx*v[2];
    float uz = qx*v[1] - qy*v[0];
    float uux = qy*uz - qz*uy;
    float uuy = qz*ux - qx*uz;
    float uuz = qx*uy - qy*ux;
    out[0] = v[0] + 2.0f*(qw*ux + uux);
    out[1] = v[1] + 2.0f*(qw*uy + uuy);
    out[2] = v[2] + 2.0f*(qw*uz + uuz);
}

// ---------- tiled-GEMM core (NN-layout B[k][n]): 64x64, BK=32, 256 thr, 4x4/thread ----------
__device__ __forceinline__ void gemm_tiles(const float* __restrict__ A, int lda,
                                           const float* __restrict__ B, int ldb,
                                           int m0, int n0, int k0, int nk,
                                           float acc[4][4], float* AsT, float* Bs) {
    int t = threadIdx.x;
    int tx = t & 15, ty = t >> 4;
    int arow = t >> 3, ak4 = (t & 7) << 2;
    int brow = t >> 4, bc4 = (t & 15) << 2;
    const float* Ap0 = A + (size_t)(m0 + arow)*lda + ak4;
    const float* Ap1 = A + (size_t)(m0 + arow + 32)*lda + ak4;
    const float* Bp0 = B + (size_t)brow*ldb + n0 + bc4;
    const float* Bp1 = B + (size_t)(brow + 16)*ldb + n0 + bc4;
    float4 a0 = *(const float4*)(Ap0 + k0);
    float4 a1 = *(const float4*)(Ap1 + k0);
    float4 b0 = *(const float4*)(Bp0 + (size_t)k0*ldb);
    float4 b1 = *(const float4*)(Bp1 + (size_t)k0*ldb);
    for (int kc = 0; kc < nk; kc++) {
        AsT[(ak4+0)*68 + arow] = a0.x;
        AsT[(ak4+1)*68 + arow] = a0.y;
        AsT[(ak4+2)*68 + arow] = a0.z;
        AsT[(ak4+3)*68 + arow] = a0.w;
        AsT[(ak4+0)*68 + arow+32] = a1.x;
        AsT[(ak4+1)*68 + arow+32] = a1.y;
        AsT[(ak4+2)*68 + arow+32] = a1.z;
        AsT[(ak4+3)*68 + arow+32] = a1.w;
        *(float4*)(Bs + brow*64 + bc4) = b0;
        *(float4*)(Bs + (brow+16)*64 + bc4) = b1;
        __syncthreads();
        if (kc + 1 < nk) {
            int kb = k0 + (kc+1)*32;
            a0 = *(const float4*)(Ap0 + kb);
            a1 = *(const float4*)(Ap1 + kb);
            b0 = *(const float4*)(Bp0 + (size_t)kb*ldb);
            b1 = *(const float4*)(Bp1 + (size_t)kb*ldb);
        }
        #pragma unroll
        for (int kk = 0; kk < 32; kk++) {
            float4 av = *(const float4*)(AsT + kk*68 + ty*4);
            float4 bv = *(const float4*)(Bs + kk*64 + tx*4);
            acc[0][0] += av.x*bv.x; acc[0][1] += av.x*bv.y; acc[0][2] += av.x*bv.z; acc[0][3] += av.x*bv.w;
            acc[1][0] += av.y*bv.x; acc[1][1] += av.y*bv.y; acc[1][2] += av.y*bv.z; acc[1][3] += av.y*bv.w;
            acc[2][0] += av.z*bv.x; acc[2][1] += av.z*bv.y; acc[2][2] += av.z*bv.z; acc[2][3] += av.z*bv.w;
            acc[3][0] += av.w*bv.x; acc[3][1] += av.w*bv.y; acc[3][2] += av.w*bv.z; acc[3][3] += av.w*bv.w;
        }
        __syncthreads();
    }
}

// ---------- NT variant: A[m][k], B[n][k] both row-major over k ----------
__device__ __forceinline__ void gemm_tiles_nt(const float* __restrict__ A,
                                              const float* __restrict__ B, int ldk,
                                              int m0, int n0, int nk,
                                              float acc[4][4], float* AsT, float* BsT) {
    int t = threadIdx.x;
    int tx = t & 15, ty = t >> 4;
    int arow = t >> 3, ak4 = (t & 7) << 2;
    const float* Ap0 = A + (size_t)(m0 + arow)*ldk + ak4;
    const float* Ap1 = A + (size_t)(m0 + arow + 32)*ldk + ak4;
    const float* Bp0 = B + (size_t)(n0 + arow)*ldk + ak4;
    const float* Bp1 = B + (size_t)(n0 + arow + 32)*ldk + ak4;
    float4 a0 = *(const float4*)(Ap0);
    float4 a1 = *(const float4*)(Ap1);
    float4 b0 = *(const float4*)(Bp0);
    float4 b1 = *(const float4*)(Bp1);
    for (int kc = 0; kc < nk; kc++) {
        AsT[(ak4+0)*68 + arow] = a0.x;
        AsT[(ak4+1)*68 + arow] = a0.y;
        AsT[(ak4+2)*68 + arow] = a0.z;
        AsT[(ak4+3)*68 + arow] = a0.w;
        AsT[(ak4+0)*68 + arow+32] = a1.x;
        AsT[(ak4+1)*68 + arow+32] = a1.y;
        AsT[(ak4+2)*68 + arow+32] = a1.z;
        AsT[(ak4+3)*68 + arow+32] = a1.w;
        BsT[(ak4+0)*68 + arow] = b0.x;
        BsT[(ak4+1)*68 + arow] = b0.y;
        BsT[(ak4+2)*68 + arow] = b0.z;
        BsT[(ak4+3)*68 + arow] = b0.w;
        BsT[(ak4+0)*68 + arow+32] = b1.x;
        BsT[(ak4+1)*68 + arow+32] = b1.y;
        BsT[(ak4+2)*68 + arow+32] = b1.z;
        BsT[(ak4+3)*68 + arow+32] = b1.w;
        __syncthreads();
        if (kc + 1 < nk) {
            int kb = (kc+1)*32;
            a0 = *(const float4*)(Ap0 + kb);
            a1 = *(const float4*)(Ap1 + kb);
            b0 = *(const float4*)(Bp0 + kb);
            b1 = *(const float4*)(Bp1 + kb);
        }
        #pragma unroll
        for (int kk = 0; kk < 32; kk++) {
            float4 av = *(const float4*)(AsT + kk*68 + ty*4);
            float4 bv = *(const float4*)(BsT + kk*68 + tx*4);
            acc[0][0] += av.x*bv.x; acc[0][1] += av.x*bv.y; acc[0][2] += av.x*bv.z; acc[0][3] += av.x*bv.w;
            acc[1][0] += av.y*bv.x; acc[1][1] += av.y*bv.y; acc[1][2] += av.y*bv.z; acc[1][3] += av.y*bv.w;
            acc[2][0] += av.z*bv.x; acc[2][1] += av.z*bv.y; acc[2][2] += av.z*bv.z; acc[2][3] += av.z*bv.w;
            acc[3][0] += av.w*bv.x; acc[3][1] += av.w*bv.y; acc[3][2] += av.w*bv.z; acc[3][3] += av.w*bv.w;
        }
        __syncthreads();
    }
}

// ---------------- kernels ----------------

__global__ void k_prep(const float* __restrict__ T, float* __restrict__ qn, float* __restrict__ tr) {
    int n = blockIdx.x*blockDim.x + threadIdx.x;
    if (n >= NN) return;
    float q0=T[n*16+0], q1=T[n*16+1], q2=T[n*16+2], q3=T[n*16+3];
    float inv = 1.0f/sqrtf(q0*q0+q1*q1+q2*q2+q3*q3 + EPSV);
    qn[n*4+0]=q0*inv; qn[n*4+1]=q1*inv; qn[n*4+2]=q2*inv; qn[n*4+3]=q3*inv;
    tr[n*3+0]=T[n*16+4]; tr[n*3+1]=T[n*16+5]; tr[n*3+2]=T[n*16+6];
}

// all five projections in one launch; blockIdx.y segments the output space
__global__ __launch_bounds__(256) void k_proj_all(const float* __restrict__ s,
    const float* __restrict__ W_q,  const float* __restrict__ b_q,  float* __restrict__ qbuf,
    const float* __restrict__ W_kv, const float* __restrict__ b_kv, float* __restrict__ kvb,
    const float* __restrict__ W_qp, const float* __restrict__ b_qp, float* __restrict__ qpr,
    const float* __restrict__ W_kp, const float* __restrict__ b_kp, float* __restrict__ kpr,
    const float* __restrict__ W_vg, const float* __restrict__ b_vg, float* __restrict__ vgr) {
    __shared__ float AsT[32*68];
    __shared__ float Bs[32*64];
    int ny = blockIdx.y;
    const float* W; const float* bias; float* C; int N; int n0;
    if (ny < 16)      { W=W_q;  bias=b_q;  C=qbuf; N=1024; n0=ny*64; }
    else if (ny < 48) { W=W_kv; bias=b_kv; C=kvb;  N=2048; n0=(ny-16)*64; }
    else if (ny < 51) { W=W_qp; bias=b_qp; C=qpr;  N=192;  n0=(ny-48)*64; }
    else if (ny < 54) { W=W_kp; bias=b_kp; C=kpr;  N=192;  n0=(ny-51)*64; }
    else              { W=W_vg; bias=b_vg; C=vgr;  N=128;  n0=(ny-54)*64; }
    int m0 = blockIdx.x*64;
    float acc[4][4] = {};
    gemm_tiles(s, CSD, W, N, m0, n0, 0, 12, acc, AsT, Bs);
    int tx = threadIdx.x & 15, ty = threadIdx.x >> 4;
    float4 bb = *(const float4*)(bias + n0 + tx*4);
    #pragma unroll
    for (int rr = 0; rr < 4; rr++) {
        float4 o = make_float4(acc[rr][0]+bb.x, acc[rr][1]+bb.y, acc[rr][2]+bb.z, acc[rr][3]+bb.w);
        *(float4*)(C + (size_t)(m0+ty*4+rr)*N + n0 + tx*4) = o;
    }
}

// merged: q-points, k-points, vg  (blockIdx.y selects task)
__global__ __launch_bounds__(64) void k_geom(const float* __restrict__ qpr,
        const float* __restrict__ kpr, const float* __restrict__ vgr,
        const float* __restrict__ g, const float* __restrict__ W_mg,
        const float* __restrict__ qn, const float* __restrict__ tr,
        float* __restrict__ qpts, float* __restrict__ Qsq,
        float* __restrict__ kpts, float* __restrict__ Ksq, float* __restrict__ vgg) {
    int n = blockIdx.x, ny = blockIdx.y, m = threadIdx.x;
    float q[4] = {qn[n*4],qn[n*4+1],qn[n*4+2],qn[n*4+3]};
    float t0=tr[n*3], t1=tr[n*3+1], t2=tr[n*3+2];
    if (ny < 2) {
        const float* raw = ny ? kpr : qpr;
        float* pts = ny ? kpts : qpts;
        float* sq  = ny ? Ksq : Qsq;
        float p[3] = {raw[n*192 + m], raw[n*192 + 64 + m], raw[n*192 + 128 + m]};
        float r[3]; qrot(q,p,r);
        r[0]+=t0; r[1]+=t1; r[2]+=t2;
        pts[n*192+m*3+0]=r[0]; pts[n*192+m*3+1]=r[1]; pts[n*192+m*3+2]=r[2];
        float s = r[0]*r[0]+r[1]*r[1]+r[2]*r[2];
        s += __shfl_down(s,4,8);
        s += __shfl_down(s,2,8);
        s += __shfl_down(s,1,8);
        if ((m&7)==0) sq[n*8 + (m>>3)] = s;
    } else {
        int o = m;
        float in[16];
        #pragma unroll
        for (int c=0;c<16;c++){
            float acc=0.0f;
            #pragma unroll
            for (int i=0;i<8;i++)  acc += W_mg[o*16+i]*vgr[n*128+i*16+c];
            #pragma unroll
            for (int i=8;i<16;i++) acc += W_mg[o*16+i]*g[n*128+(i-8)*16+c];
            in[c]=acc;
        }
        float out[16];
        out[0]=in[0];
        qrot(q,in+1,out+1);
        qrot(q,in+4,out+4);
        float w=in[10];
        qrot(q,in+7,out+7);
        out[7]+=w*t0; out[8]+=w*t1; out[9]+=w*t2;
        #pragma unroll
        for (int c=10;c<16;c++) out[c]=in[c];
        #pragma unroll
        for (int c=0;c<16;c++) vgg[(size_t)n*1024+o*16+c]=out[c];
    }
}

// build fused score operands: U[h][i][160], Vr[h][j][160] (BOTH row-major), row/col terms
__global__ __launch_bounds__(256) void k_uv(const float* __restrict__ qbuf, const float* __restrict__ kvb,
                    const float* __restrict__ qpts, const float* __restrict__ kpts,
                    const float* __restrict__ Qsq, const float* __restrict__ Ksq,
                    const float* __restrict__ hwraw, const float* __restrict__ b_b,
                    float* __restrict__ U, float* __restrict__ Vr,
                    float* __restrict__ rowt, float* __restrict__ colt) {
    int i = blockIdx.x; int t = threadIdx.x;
    #pragma unroll
    for (int h = 0; h < 8; h++) {
        float hw = log1pf(expf(hwraw[h])) * 0.09622504486493763f; // softplus * sqrt(1/108)
        if (t < 160) {
            float u, v;
            if (t < 128) {
                u = 0.05103103630798287f * qbuf[(size_t)i*1024 + h*128 + t]; // sqrt(1/384)
                v = kvb[(size_t)i*2048 + h*256 + t];
            } else if (t < 152) {
                int d = t - 128;
                u = hw * qpts[i*192 + h*24 + d];
                v = kpts[i*192 + h*24 + d];
            } else { u = 0.0f; v = 0.0f; }
            U [((size_t)h*512 + i)*160 + t] = u;
            Vr[((size_t)h*512 + i)*160 + t] = v;
        }
        if (t == 160) rowt[h*512+i] = -0.5f*hw*Qsq[i*8+h] + 0.5773502691896258f*b_b[h] - INFV;
        if (t == 161) colt[h*512+i] = -0.5f*hw*Ksq[i*8+h];
    }
}

// zb[h][i][j] = sum_c z[i,j,c] * W_b[c,h]
__global__ __launch_bounds__(128) void k_zb(const float* __restrict__ z,
        const float* __restrict__ W_b, float* __restrict__ zb) {
    __shared__ float zt[64*132];
    __shared__ float part[8*64];
    int i = blockIdx.x, j0 = blockIdx.y*64;
    int t = threadIdx.x; // 128
    #pragma unroll
    for (int l = 0; l < 16; l++) {
        int f = t + l*128;                 // 64 rows x 32 f4
        int row = f >> 5, c4 = (f & 31) << 2;
        float4 v = *(const float4*)(z + ((size_t)(i*NN) + j0 + row)*CZD + c4);
        *(float4*)(zt + row*132 + c4) = v;
    }
    __syncthreads();
    int w = t >> 6, j = t & 63;            // wave splits c-range (wave-uniform)
    int cbase = w*64;
    float acc[8] = {};
    #pragma unroll
    for (int c16 = 0; c16 < 16; c16++) {
        float4 v = *(const float4*)(zt + j*132 + cbase + c16*4);
        int c = cbase + c16*4;
        #pragma unroll
        for (int h = 0; h < 8; h++)
            acc[h] += v.x*W_b[(c+0)*8+h] + v.y*W_b[(c+1)*8+h]
                    + v.z*W_b[(c+2)*8+h] + v.w*W_b[(c+3)*8+h];
    }
    if (w == 1) {
        #pragma unroll
        for (int h = 0; h < 8; h++) part[h*64 + j] = acc[h];
    }
    __syncthreads();
    if (w == 0) {
        #pragma unroll
        for (int h = 0; h < 8; h++)
            zb[((size_t)h*512 + i)*512 + j0 + j] = acc[h] + part[h*64 + j];
    }
}

// raw scores via K=160 NT GEMM + affine epilogue
__global__ __launch_bounds__(256) void k_scorefill(const float* __restrict__ U, const float* __restrict__ Vr,
        const float* __restrict__ rowt, const float* __restrict__ colt,
        const float* __restrict__ zb, const float* __restrict__ mask,
        const float* __restrict__ sw, float* __restrict__ Am) {
    __shared__ float AsT[32*68];
    __shared__ float BsT[32*68];
    int h = blockIdx.z;
    int m0 = blockIdx.x*64, n0 = blockIdx.y*64;
    float acc[4][4] = {};
    gemm_tiles_nt(U + (size_t)h*512*160, Vr + (size_t)h*512*160, 160, m0, n0, 5, acc, AsT, BsT);
    int tx = threadIdx.x & 15, ty = threadIdx.x >> 4;
    float swh = sw[h];
    float4 ct = *(const float4*)(colt + h*512 + n0 + tx*4);
    float4 mj = *(const float4*)(mask + n0 + tx*4);
    #pragma unroll
    for (int rr = 0; rr < 4; rr++) {
        int i = m0 + ty*4 + rr;
        float rt = rowt[h*512 + i];
        float mi = mask[i] * INFV;
        float4 zv = *(const float4*)(zb + ((size_t)h*512 + i)*512 + n0 + tx*4);
        float4 r;
        r.x = (acc[rr][0] + rt + ct.x + 0.5773502691896258f*zv.x + mi*mj.x)*swh;
        r.y = (acc[rr][1] + rt + ct.y + 0.5773502691896258f*zv.y + mi*mj.y)*swh;
        r.z = (acc[rr][2] + rt + ct.z + 0.5773502691896258f*zv.z + mi*mj.z)*swh;
        r.w = (acc[rr][3] + rt + ct.w + 0.5773502691896258f*zv.w + mi*mj.w)*swh;
        *(float4*)(Am + ((size_t)h*512 + i)*512 + n0 + tx*4) = r;
    }
}

// pack Vp[h][j][0:128]=kv-v, [128:256]=vgg  (into dead zb region)
__global__ __launch_bounds__(256) void k_pack(const float* __restrict__ kvb,
        const float* __restrict__ vgg, float* __restrict__ Vp) {
    int idx = blockIdx.x*256 + threadIdx.x;   // 262144 float4s
    int c4 = idx & 63, j = (idx >> 6) & 511, h = idx >> 15;
    int col = c4*4;
    float4 v;
    if (col < 128) v = *(const float4*)(kvb + (size_t)j*2048 + h*256 + 128 + col);
    else           v = *(const float4*)(vgg + (size_t)j*1024 + h*128 + col - 128);
    *(float4*)(Vp + ((size_t)h*512 + j)*256 + col) = v;
}

// softmax over each (h,i) row, in-place; fuses the S-moments (o_rel reduction)
__global__ __launch_bounds__(256) void k_softmax(float* __restrict__ Am,
        const float* __restrict__ qn, const float* __restrict__ tr, float* __restrict__ S) {
    __shared__ float red[8];
    __shared__ float sred[4][8];
    int row = blockIdx.x;           // h*512 + i
    float* p = Am + (size_t)row*512;
    int t = threadIdx.x;            // 256
    float x0 = p[t], x1 = p[t+256];
    float m = fmaxf(x0, x1);
    #pragma unroll
    for (int o = 32; o > 0; o >>= 1) m = fmaxf(m, __shfl_xor(m, o));
    int wv = t >> 6, ln = t & 63;
    if (ln == 0) red[wv] = m;
    __syncthreads();
    m = fmaxf(fmaxf(red[0], red[1]), fmaxf(red[2], red[3]));
    float e0 = expf(x0 - m), e1 = expf(x1 - m);
    float sm = e0 + e1;
    #pragma unroll
    for (int o = 32; o > 0; o >>= 1) sm += __shfl_xor(sm, o);
    __syncthreads();
    if (ln == 0) red[4 + wv] = sm;
    __syncthreads();
    float inv = 1.0f / (red[4]+red[5]+red[6]+red[7]);
    float a0 = e0*inv, a1 = e1*inv;
    p[t] = a0;
    p[t+256] = a1;
    float4 q0 = *(const float4*)(qn + t*4);
    float4 q1 = *(const float4*)(qn + (t+256)*4);
    float acc[8];
    acc[0] = a0*q0.x + a1*q1.x;
    acc[1] = a0*q0.y + a1*q1.y;
    acc[2] = a0*q0.z + a1*q1.z;
    acc[3] = a0*q0.w + a1*q1.w;
    acc[4] = a0*tr[t*3+0] + a1*tr[(t+256)*3+0];
    acc[5] = a0*tr[t*3+1] + a1*tr[(t+256)*3+1];
    acc[6] = a0*tr[t*3+2] + a1*tr[(t+256)*3+2];
    acc[7] = a0 + a1;
    #pragma unroll
    for (int c = 0; c < 8; c++) {
        #pragma unroll
        for (int o = 32; o > 0; o >>= 1) acc[c] += __shfl_xor(acc[c], o);
    }
    if (ln == 0) {
        #pragma unroll
        for (int c = 0; c < 8; c++) sred[wv][c] = acc[c];
    }
    __syncthreads();
    if (t < 8) {
        int h = row >> 9, i = row & 511;
        S[i*64 + h*8 + t] = sred[0][t]+sred[1][t]+sred[2][t]+sred[3][t];
    }
}

// o and o_g as GEMM: C[h][512x256] = Am[h][512x512] x Vp[h][512x256], j-split 4, atomics
__global__ __launch_bounds__(256) void k_apply(const float* __restrict__ Am,
        const float* __restrict__ Vp, float* __restrict__ obuf, float* __restrict__ og) {
    __shared__ float AsT[32*68];
    __shared__ float Bs[32*64];
    int m0 = blockIdx.x*64;             // i tile
    int n0 = blockIdx.y*64;             // col tile (0..255)
    int h = blockIdx.z & 7, js = blockIdx.z >> 3;
    float acc[4][4] = {};
    gemm_tiles(Am + (size_t)h*512*512, 512, Vp + (size_t)h*512*256, 256,
               m0, n0, js*128, 4, acc, AsT, Bs);
    int tx = threadIdx.x & 15, ty = threadIdx.x >> 4;
    float* base = (n0 < 128) ? (obuf + h*128 + n0) : (og + h*128 + n0 - 128);
    #pragma unroll
    for (int rr = 0; rr < 4; rr++) {
        #pragma unroll
        for (int cc = 0; cc < 4; cc++)
            atomicAdd(base + (size_t)(m0+ty*4+rr)*1024 + tx*4 + cc, acc[rr][cc]);
    }
}

// az[i][h][zc] += sum_j a[h,i,j] * z[i,j,zc]  -- j-split 4, az pre-zeroed
__global__ __launch_bounds__(128) void k_az(const float* __restrict__ Am,
        const float* __restrict__ z, float* __restrict__ az) {
    __shared__ float aT[128*8];     // [j_local][h]
    int i = blockIdx.x, j0 = blockIdx.y*128, t = threadIdx.x;
    #pragma unroll
    for (int l = 0; l < 8; l++) {
        int f = t + l*128;          // h-major: consecutive t -> consecutive j (coalesced)
        int h = f >> 7, jl = f & 127;
        aT[jl*8 + h] = Am[((size_t)h*512 + i)*512 + j0 + jl];
    }
    __syncthreads();
    float acc[8] = {};
    const float* zp = z + ((size_t)i*NN + j0)*CZD + t;
    for (int jl = 0; jl < 128; jl++) {
        float zv = zp[(size_t)jl*CZD];
        float4 a0 = *(const float4*)(aT + jl*8);
        float4 a1 = *(const float4*)(aT + jl*8 + 4);
        acc[0] += a0.x*zv; acc[1] += a0.y*zv; acc[2] += a0.z*zv; acc[3] += a0.w*zv;
        acc[4] += a1.x*zv; acc[5] += a1.y*zv; acc[6] += a1.z*zv; acc[7] += a1.w*zv;
    }
    #pragma unroll
    for (int h = 0; h < 8; h++)
        atomicAdd(az + (size_t)i*1024 + h*128 + t, acc[h]);
}

// one dense block per i: o copy, o_pair (LDS W_dz), quat epilogue, o_rel
__global__ __launch_bounds__(256) void k_finalize(const float* __restrict__ obuf,
        const float* __restrict__ az, const float* __restrict__ W_dz,
        const float* __restrict__ b_dz, float* __restrict__ og,
        const float* __restrict__ S, const float* __restrict__ qn,
        const float* __restrict__ tr, float* __restrict__ feats) {
    __shared__ float azs[1024];
    __shared__ float wdz[4096];
    int i = blockIdx.x, t = threadIdx.x; // 256
    float* fb = feats + (size_t)i*2496;
    for (int idx = t; idx < 1024; idx += 256) {
        azs[idx] = az[(size_t)i*1024 + idx];
        int h = idx >> 7, c = idx & 127;
        fb[h*312 + 32 + c] = obuf[(size_t)i*1024 + idx];
    }
    for (int idx = t; idx < 4096; idx += 256) wdz[idx] = W_dz[idx];
    __syncthreads();
    {   // o_pair: all 256 threads (h = t>>5, m = t&31)
        int h = t >> 5, m = t & 31;
        float acc = b_dz[m];
        #pragma unroll 8
        for (int zc = 0; zc < 128; zc++) acc += azs[h*128+zc]*wdz[zc*32+m];
        fb[h*312 + m] = acc;
    }
    float qc[4] = {qn[i*4], -qn[i*4+1], -qn[i*4+2], -qn[i*4+3]};
    float t0 = tr[i*3], t1 = tr[i*3+1], t2 = tr[i*3+2];
    if (t < 64) {   // quat inverse-transform + norms: (h = t>>3, p = t&7)
        int h = t >> 3, p = t & 7;
        float* f = fb + h*312;
        float* ogp = og + (size_t)i*1024 + h*128 + p*16;
        float in[16];
        #pragma unroll
        for (int c=0;c<16;c++) in[c]=ogp[c];
        float out[16];
        out[0]=in[0];
        qrot(qc,in+1,out+1);
        qrot(qc,in+4,out+4);
        float w=in[10];
        float tmp[3]={in[7]-w*t0, in[8]-w*t1, in[9]-w*t2};
        qrot(qc,tmp,out+7);
        #pragma unroll
        for (int c2=10;c2<16;c2++) out[c2]=in[c2];
        float n1=EPSV, n2=EPSV;
        #pragma unroll
        for (int c2=0;c2<10;c2++) n1 += out[c2]*out[c2];
        #pragma unroll
        for (int c2=10;c2<16;c2++) n2 += out[c2]*out[c2];
        n1=sqrtf(n1); n2=sqrtf(n2);
        #pragma unroll
        for (int c2=0;c2<16;c2++){ f[168+p*16+c2]=out[c2]; ogp[c2]=out[c2]; }
        f[296+p*2]=n1; f[296+p*2+1]=n2;
    } else if (t < 72) {    // o_rel from S-moments: h = t-64
        int h = t - 64;
        float* f = fb + h*312;
        const float* Sr = S + i*64 + h*8;
        float b0=Sr[0], b1=Sr[1], b2=Sr[2], b3=Sr[3];
        f[160] = qc[0]*b0 - qc[1]*b1 - qc[2]*b2 - qc[3]*b3;
        f[161] = qc[0]*b1 + qc[1]*b0 + qc[2]*b3 - qc[3]*b2;
        f[162] = qc[0]*b2 - qc[1]*b3 + qc[2]*b0 + qc[3]*b1;
        f[163] = qc[0]*b3 + qc[1]*b2 - qc[2]*b1 + qc[3]*b0;
        float A = Sr[7];
        float v[3]={Sr[4]-A*t0, Sr[5]-A*t1, Sr[6]-A*t2};
        float r[3]; qrot(qc,v,r);
        f[164]=r[0]; f[165]=r[1]; f[166]=r[2]; f[167]=0.0f;
    }
}

__global__ __launch_bounds__(256) void k_gout(const float* __restrict__ og, const float* __restrict__ W_geo,
                       float* __restrict__ gout) {
    int idx = blockIdx.x*blockDim.x+threadIdx.x; // 65536
    int c = idx & 15;
    int o = (idx>>4) & 7;
    int n = idx >> 7;
    float acc=0.0f;
    #pragma unroll 4
    for (int i2=0;i2<64;i2++) acc += W_geo[o*64+i2]*og[(size_t)n*1024 + i2*16 + c];
    gout[(size_t)n*128 + o*16 + c]=acc;
}

// s_out: split-K 13 tiled GEMM with atomic accumulation (out pre-zeroed)
__global__ __launch_bounds__(256) void k_sout(const float* __restrict__ feats,
        const float* __restrict__ W_out, const float* __restrict__ b_out, float* __restrict__ out) {
    __shared__ float AsT[32*68];
    __shared__ float Bs[32*64];
    int m0 = blockIdx.x*64, n0 = blockIdx.y*64, kz = blockIdx.z;
    float acc[4][4] = {};
    gemm_tiles(feats, 2496, W_out, CSD, m0, n0, kz*192, 6, acc, AsT, Bs);
    int tx = threadIdx.x & 15, ty = threadIdx.x >> 4;
    #pragma unroll
    for (int rr = 0; rr < 4; rr++) {
        #pragma unroll
        for (int cc = 0; cc < 4; cc++) {
            float v = acc[rr][cc];
            if (kz == 0) v += b_out[n0 + tx*4 + cc];
            atomicAdd(out + (size_t)(m0+ty*4+rr)*CSD + n0 + tx*4 + cc, v);
        }
    }
}

// ---------------- launch ----------------

extern "C" void kernel_launch(void* const* d_in, const int* in_sizes, int n_in,
                              void* d_out, int out_size, void* d_ws, size_t ws_size,
                              hipStream_t stream) {
    const float* s     = (const float*)d_in[0];
    const float* g     = (const float*)d_in[1];
    const float* z     = (const float*)d_in[2];
    const float* T     = (const float*)d_in[3];
    const float* mask  = (const float*)d_in[4];
    const float* W_q   = (const float*)d_in[5];
    const float* b_q   = (const float*)d_in[6];
    const float* W_kv  = (const float*)d_in[7];
    const float* b_kv  = (const float*)d_in[8];
    const float* W_qp  = (const float*)d_in[9];
    const float* b_qp  = (const float*)d_in[10];
    const float* W_kp  = (const float*)d_in[11];
    const float* b_kp  = (const float*)d_in[12];
    const float* W_vg  = (const float*)d_in[13];
    const float* b_vg  = (const float*)d_in[14];
    const float* W_mg  = (const float*)d_in[15];
    const float* W_b   = (const float*)d_in[16];
    const float* b_b   = (const float*)d_in[17];
    const float* W_dz  = (const float*)d_in[18];
    const float* b_dz  = (const float*)d_in[19];
    const float* hw    = (const float*)d_in[20];
    const float* sw    = (const float*)d_in[21];
    const float* W_out = (const float*)d_in[22];
    const float* b_out = (const float*)d_in[23];
    const float* W_geo = (const float*)d_in[24];

    float* ws   = (float*)d_ws;
    float* out  = (float*)d_out;

    float* qn   = ws + OFF_QN;
    float* tr   = ws + OFF_TR;
    float* Qsq  = ws + OFF_QSQ;
    float* Ksq  = ws + OFF_KSQ;
    float* rowt = ws + OFF_ROWT;
    float* colt = ws + OFF_COLT;
    float* Sbuf = ws + OFF_SB;
    float* qbuf = ws + OFF_QBUF;
    float* kvb  = ws + OFF_KV;
    float* qpts = ws + OFF_QPTS;
    float* kpts = ws + OFF_KPTS;
    float* vgg  = ws + OFF_VGG;
    float* zb   = ws + OFF_ZB;
    float* Am   = ws + OFF_A;
    float* qpr  = ws + OFF_QPR;
    float* kpr  = ws + OFF_KPR;
    float* vgr  = ws + OFF_VGR;
    float* U    = ws + OFF_U;
    float* Vr   = ws + OFF_V;
    float* az   = ws + OFF_AZ;
    float* obuf = ws + OFF_O;
    float* og   = ws + OFF_OG;
    float* feats= ws + OFF_FEATS;
    float* Vp   = ws + OFF_VP;

    k_prep<<<2,256,0,stream>>>(T,qn,tr);
    k_proj_all<<<dim3(8,56),256,0,stream>>>(s, W_q,b_q,qbuf, W_kv,b_kv,kvb,
                                            W_qp,b_qp,qpr, W_kp,b_kp,kpr, W_vg,b_vg,vgr);
    k_geom<<<dim3(NN,3),64,0,stream>>>(qpr,kpr,vgr,g,W_mg,qn,tr,qpts,Qsq,kpts,Ksq,vgg);
    k_uv<<<NN,256,0,stream>>>(qbuf,kvb,qpts,kpts,Qsq,Ksq,hw,b_b,U,Vr,rowt,colt);
    k_zb<<<dim3(NN,8),128,0,stream>>>(z,W_b,zb);
    k_scorefill<<<dim3(8,8,8),256,0,stream>>>(U,Vr,rowt,colt,zb,mask,sw,Am);
    // U/Vr/zb dead from here; az+obuf+og overlay that space -> zero in one shot
    k_pack<<<1024,256,0,stream>>>(kvb,vgg,Vp);
    hipMemsetAsync(ws + OFF_X, 0, (size_t)3*512*1024*sizeof(float), stream);
    k_softmax<<<4096,256,0,stream>>>(Am,qn,tr,Sbuf);
    k_apply<<<dim3(8,4,32),256,0,stream>>>(Am,Vp,obuf,og);
    k_az<<<dim3(NN,4),128,0,stream>>>(Am,z,az);
    k_finalize<<<NN,256,0,stream>>>(obuf,az,W_dz,b_dz,og,Sbuf,qn,tr,feats);
    k_gout<<<256,256,0,stream>>>(og,W_geo,out + (size_t)NN*CSD);
    hipMemsetAsync(out, 0, (size_t)NN*CSD*sizeof(float), stream);
    k_sout<<<dim3(8,6,13),256,0,stream>>>(feats,W_out,b_out,out);
}